// Round 4
// baseline (5767.508 us; speedup 1.0000x reference)
//
#include <hip/hip_runtime.h>
#include <math.h>

#define B_ 32
#define S_ 50
#define H_ 256
#define T_ 25
#define V_ 50257
#define NCH 786   /* ceil(V/64) */
#define SOS 0

// ---- static device scratch: loader-allocated, guaranteed valid.
__device__ float g_ua[B_ * S_ * H_];    // 1.6 MB
__device__ float g_h[B_ * H_];          // 32 KB
__device__ float g_pmax[B_ * NCH];      // 100 KB
__device__ float g_psum[B_ * NCH];      // 100 KB

// ---------------- one-time: ua[b,s,g] = keys[b,s,:] . Ua_w[g,:] + Ua_b[g]
__global__ void k_ua(const float* __restrict__ keys, const float* __restrict__ Ua_w,
                     const float* __restrict__ Ua_b) {
  __shared__ float sk[H_];
  const int row = blockIdx.x;   // b*S_+s
  const int g = threadIdx.x;
  sk[g] = keys[row * H_ + g];
  __syncthreads();
  float acc = Ua_b[g];
  const float4* wrow = (const float4*)(Ua_w + (size_t)g * H_);
  const float4* sk4 = (const float4*)sk;
  for (int k = 0; k < H_ / 4; ++k) {
    const float4 w = wrow[k];
    const float4 x = sk4[k];
    acc += w.x * x.x + w.y * x.y + w.z * x.z + w.w * x.w;
  }
  g_ua[(size_t)row * H_ + g] = acc;
}

// ---------------- per step: attention + GRU. one block per batch row.
__global__ void k_step(const float* __restrict__ enc_h, const int* __restrict__ tgt,
                       const float* __restrict__ emb_tab,
                       const float* __restrict__ Wa_w, const float* __restrict__ Wa_b,
                       const float* __restrict__ Va_w, const float* __restrict__ Va_b,
                       const float* __restrict__ keys,
                       const float* __restrict__ W_ih, const float* __restrict__ b_ih,
                       const float* __restrict__ W_hh, const float* __restrict__ b_hh,
                       float* __restrict__ out, int t) {
  __shared__ float sh[H_];      // old h
  __shared__ float sx[2 * H_];  // [emb, ctx]
  __shared__ float swaq[H_];
  __shared__ float sva[H_];
  __shared__ float sscore[64];
  __shared__ float sw[64];
  const int b = blockIdx.x, g = threadIdx.x;
  const int lane = g & 63, wid = g >> 6;

  const float hold = (t == 0) ? enc_h[b * H_ + g] : g_h[b * H_ + g];
  sh[g] = hold;
  const int tok = (t == 0) ? SOS : tgt[b * T_ + (t - 1)];
  sx[g] = emb_tab[(size_t)tok * H_ + g];
  sva[g] = Va_w[g];
  __syncthreads();

  // wa_q[g] = h . Wa_w[g,:] + Wa_b[g]
  {
    float acc = Wa_b[g];
    const float4* wrow = (const float4*)(Wa_w + (size_t)g * H_);
    const float4* sh4 = (const float4*)sh;
    for (int k = 0; k < H_ / 4; ++k) {
      const float4 w = wrow[k];
      const float4 x = sh4[k];
      acc += w.x * x.x + w.y * x.y + w.z * x.z + w.w * x.w;
    }
    swaq[g] = acc;
  }
  __syncthreads();

  const float vab = Va_b[0];
  // scores[s] = sum_g tanh(waq[g]+ua[b,s,g]) * Va[g] + Va_b ; waves split s
  for (int s = wid; s < S_; s += 4) {
    const float* uarow = g_ua + (size_t)(b * S_ + s) * H_;
    float acc = 0.f;
#pragma unroll
    for (int i = 0; i < 4; ++i) {
      const int gg = lane + i * 64;
      acc += tanhf(swaq[gg] + uarow[gg]) * sva[gg];
    }
    for (int off = 32; off > 0; off >>= 1) acc += __shfl_down(acc, off);
    if (lane == 0) sscore[s] = acc + vab;
  }
  __syncthreads();

  // softmax over S (wave 0) + write attentions
  if (g < 64) {
    const float v = (g < S_) ? sscore[g] : -INFINITY;
    float m = v;
    for (int off = 32; off > 0; off >>= 1) m = fmaxf(m, __shfl_xor(m, off));
    const float e = (g < S_) ? expf(v - m) : 0.f;
    float ssum = e;
    for (int off = 32; off > 0; off >>= 1) ssum += __shfl_xor(ssum, off);
    const float w = e / ssum;
    if (g < S_) {
      sw[g] = w;
      out[(size_t)B_ * T_ * V_ + (size_t)B_ * H_ + (size_t)(b * T_ + t) * S_ + g] = w;
    }
  }
  __syncthreads();

  // ctx[g] = sum_s w[s] * keys[b,s,g]
  {
    float acc = 0.f;
    for (int s = 0; s < S_; ++s) acc += sw[s] * keys[(size_t)(b * S_ + s) * H_ + g];
    sx[H_ + g] = acc;
  }
  __syncthreads();

  // GRU: thread g computes rows g, g+256, g+512 of gi and gh
  float gi[3], gh[3];
#pragma unroll
  for (int jj = 0; jj < 3; ++jj) {
    const int j = g + jj * H_;
    float acc = b_ih[j];
    const float4* wrow = (const float4*)(W_ih + (size_t)j * (2 * H_));
    const float4* sx4 = (const float4*)sx;
    for (int k = 0; k < 2 * H_ / 4; ++k) {
      const float4 w = wrow[k];
      const float4 x = sx4[k];
      acc += w.x * x.x + w.y * x.y + w.z * x.z + w.w * x.w;
    }
    gi[jj] = acc;
    float acc2 = b_hh[j];
    const float4* wrow2 = (const float4*)(W_hh + (size_t)j * H_);
    const float4* sh4 = (const float4*)sh;
    for (int k = 0; k < H_ / 4; ++k) {
      const float4 w = wrow2[k];
      const float4 x = sh4[k];
      acc2 += w.x * x.x + w.y * x.y + w.z * x.z + w.w * x.w;
    }
    gh[jj] = acc2;
  }
  const float r = 1.f / (1.f + expf(-(gi[0] + gh[0])));
  const float z = 1.f / (1.f + expf(-(gi[1] + gh[1])));
  const float n = tanhf(gi[2] + r * gh[2]);
  const float h2 = (1.f - z) * n + z * hold;
  g_h[b * H_ + g] = h2;
  if (t == T_ - 1) out[(size_t)B_ * T_ * V_ + b * H_ + g] = h2;
}

// ---------------- per step: logits[b,v] -> f32 into dec_out slot; partials to globals
// block = 64 vocab cols x all 32 batch rows; wave w handles b in [8w, 8w+8)
__global__ void k_logits(const float* __restrict__ out_w, const float* __restrict__ out_b,
                         float* __restrict__ out, int t) {
  __shared__ float sh2[B_ * H_];
  const int tid = threadIdx.x;
  for (int i = tid; i < B_ * H_; i += 256) sh2[i] = g_h[i];
  __syncthreads();
  const int vl = tid & 63, wid = tid >> 6;
  const int v = blockIdx.x * 64 + vl;
  const bool valid = (v < V_);
  float acc[8];
  const float base = valid ? out_b[v] : 0.f;
#pragma unroll
  for (int bb = 0; bb < 8; ++bb) acc[bb] = valid ? base : -INFINITY;
  if (valid) {
    const float4* wrow = (const float4*)(out_w + (size_t)v * H_);
    const float4* sh4 = (const float4*)sh2;
    for (int k8 = 0; k8 < 32; ++k8) {
      const float4 w0 = wrow[2 * k8];
      const float4 w1 = wrow[2 * k8 + 1];
#pragma unroll
      for (int bb = 0; bb < 8; ++bb) {
        const int bidx = wid * 8 + bb;
        const float4 a = sh4[bidx * 64 + k8 * 2];
        const float4 c = sh4[bidx * 64 + k8 * 2 + 1];
        acc[bb] += w0.x * a.x + w0.y * a.y + w0.z * a.z + w0.w * a.w
                 + w1.x * c.x + w1.y * c.y + w1.z * c.z + w1.w * c.w;
      }
    }
#pragma unroll
    for (int bb = 0; bb < 8; ++bb) {
      const int bidx = wid * 8 + bb;
      out[((size_t)(bidx * T_ + t)) * V_ + v] = acc[bb];
    }
  }
  // per-wave partial max / sumexp for each of this wave's 8 batch rows
#pragma unroll
  for (int bb = 0; bb < 8; ++bb) {
    float m = acc[bb];
    for (int off = 32; off > 0; off >>= 1) m = fmaxf(m, __shfl_xor(m, off));
    const float e = valid ? expf(acc[bb] - m) : 0.f;
    float s = e;
    for (int off = 32; off > 0; off >>= 1) s += __shfl_xor(s, off);
    if (vl == 0) {
      g_pmax[(size_t)(wid * 8 + bb) * NCH + blockIdx.x] = m;
      g_psum[(size_t)(wid * 8 + bb) * NCH + blockIdx.x] = s;
    }
  }
}

// ---------------- per step: combine partials -> lse, rewrite log-softmax in place
__global__ void k_write(float* __restrict__ out, int t) {
  __shared__ float red[4];
  const int b = blockIdx.y;
  const int tid = threadIdx.x;
  float m = -INFINITY;
  for (int i = tid; i < NCH; i += 256) m = fmaxf(m, g_pmax[(size_t)b * NCH + i]);
  for (int off = 32; off > 0; off >>= 1) m = fmaxf(m, __shfl_xor(m, off));
  if ((tid & 63) == 0) red[tid >> 6] = m;
  __syncthreads();
  m = fmaxf(fmaxf(red[0], red[1]), fmaxf(red[2], red[3]));
  __syncthreads();
  float s = 0.f;
  for (int i = tid; i < NCH; i += 256)
    s += g_psum[(size_t)b * NCH + i] * expf(g_pmax[(size_t)b * NCH + i] - m);
  for (int off = 32; off > 0; off >>= 1) s += __shfl_xor(s, off);
  if ((tid & 63) == 0) red[tid >> 6] = s;
  __syncthreads();
  s = red[0] + red[1] + red[2] + red[3];
  float lse = m + logf(s);
  if (!isfinite(lse)) lse = 0.f;   // diagnostic guard: finite-but-wrong beats NaN
  const size_t obase = ((size_t)b * T_ + t) * (size_t)V_;
  const int vbase = blockIdx.x * 2048;
#pragma unroll
  for (int j = 0; j < 8; ++j) {
    const int v = vbase + j * 256 + tid;
    if (v < V_) out[obase + v] = out[obase + v] - lse;
  }
}

extern "C" void kernel_launch(void* const* d_in, const int* in_sizes, int n_in,
                              void* d_out, int out_size, void* d_ws, size_t ws_size,
                              hipStream_t stream) {
  const float* enc_h  = (const float*)d_in[0];
  const float* keys   = (const float*)d_in[1];
  const int*   tgt    = (const int*)d_in[2];
  const float* emb    = (const float*)d_in[3];
  const float* Wa_w   = (const float*)d_in[4];
  const float* Wa_b   = (const float*)d_in[5];
  const float* Ua_w   = (const float*)d_in[6];
  const float* Ua_b   = (const float*)d_in[7];
  const float* Va_w   = (const float*)d_in[8];
  const float* Va_b   = (const float*)d_in[9];
  const float* W_ih   = (const float*)d_in[10];
  const float* b_ih   = (const float*)d_in[11];
  const float* W_hh   = (const float*)d_in[12];
  const float* b_hh   = (const float*)d_in[13];
  const float* out_w  = (const float*)d_in[14];
  const float* out_b  = (const float*)d_in[15];
  float* out = (float*)d_out;
  (void)d_ws; (void)ws_size;

  hipLaunchKernelGGL(k_ua, dim3(B_ * S_), dim3(H_), 0, stream, keys, Ua_w, Ua_b);
  for (int t = 0; t < T_; ++t) {
    hipLaunchKernelGGL(k_step, dim3(B_), dim3(H_), 0, stream,
                       enc_h, tgt, emb, Wa_w, Wa_b, Va_w, Va_b, keys,
                       W_ih, b_ih, W_hh, b_hh, out, t);
    hipLaunchKernelGGL(k_logits, dim3(NCH), dim3(256), 0, stream, out_w, out_b, out, t);
    hipLaunchKernelGGL(k_write, dim3(25, B_), dim3(256), 0, stream, out, t);
  }
}

// Round 5
// 3361.546 us; speedup vs baseline: 1.7157x; 1.7157x over previous
//
#include <hip/hip_runtime.h>
#include <math.h>

#define B_ 32
#define S_ 50
#define H_ 256
#define T_ 25
#define V_ 50257
#define NCH 786   /* ceil(V/64) */
#define SOS 0

typedef unsigned short ushort_t;
typedef __attribute__((ext_vector_type(8))) unsigned short ushort8;

// ---- static device scratch (loader-allocated, deterministic; fully rewritten each call)
__device__ float    g_ua[B_ * S_ * H_];       // 1.6 MB  f32 ua_keys
__device__ float    g_wq[B_ * H_];            // wa_q (current step)
__device__ float    g_h[B_ * H_];             // h2, b-major (for k_logits staging)
__device__ float    g_hT[2][H_ * B_];         // h transposed [g][b], ping-pong by t
__device__ ushort_t g_xT[2 * H_ * B_];        // x=[emb,ctx] transposed bf16 [k][b]
__device__ ushort_t g_wbf[(size_t)V_ * H_];   // out_w bf16 (25.7 MB)
__device__ ushort_t g_wihbf[3 * H_ * 2 * H_]; // W_ih bf16
__device__ ushort_t g_whhbf[3 * H_ * H_];     // W_hh bf16
__device__ float    g_pmax[B_ * NCH];
__device__ float    g_psum[B_ * NCH];

__device__ __forceinline__ float bf2f(ushort_t h) {
  union { unsigned int u; float f; } c; c.u = ((unsigned int)h) << 16; return c.f;
}
__device__ __forceinline__ ushort_t f2bf(float f) {
  union { float f; unsigned int u; } c; c.f = f;
  unsigned int u = c.u;
  return (ushort_t)((u + 0x7FFFu + ((u >> 16) & 1u)) >> 16);
}

// ---------------- one-time: bf16 conversions of streamed weights
__global__ void k_prep(const float* __restrict__ out_w, const float* __restrict__ W_ih,
                       const float* __restrict__ W_hh) {
  const int i0 = blockIdx.x * 256 + threadIdx.x;
  const int stride = gridDim.x * 256;
  for (size_t i = i0; i < (size_t)V_ * H_; i += stride) g_wbf[i] = f2bf(out_w[i]);
  for (int i = i0; i < 3 * H_ * 2 * H_; i += stride) g_wihbf[i] = f2bf(W_ih[i]);
  for (int i = i0; i < 3 * H_ * H_; i += stride) g_whhbf[i] = f2bf(W_hh[i]);
}

// ---------------- one-time: ua[b,s,g] = keys[b,s,:] . Ua_w[g,:] + Ua_b[g]
__global__ void k_ua(const float* __restrict__ keys, const float* __restrict__ Ua_w,
                     const float* __restrict__ Ua_b) {
  __shared__ float sk[H_];
  const int row = blockIdx.x;   // b*S_+s
  const int g = threadIdx.x;
  sk[g] = keys[row * H_ + g];
  __syncthreads();
  float acc = Ua_b[g];
  const float4* wrow = (const float4*)(Ua_w + (size_t)g * H_);
  const float4* sk4 = (const float4*)sk;
  for (int k = 0; k < H_ / 4; ++k) {
    const float4 w = wrow[k];
    const float4 x = sk4[k];
    acc += w.x * x.x + w.y * x.y + w.z * x.z + w.w * x.w;
  }
  g_ua[(size_t)row * H_ + g] = acc;
}

// ---------------- one-time: wa_q(enc_h) + g_hT[0] = enc_h^T.  grid 4 x 256
__global__ void k_init(const float* __restrict__ enc_h, const float* __restrict__ Wa_w,
                       const float* __restrict__ Wa_b) {
  __shared__ float sh2[B_ * H_];
  const int tid = threadIdx.x, q = blockIdx.x;
  for (int i = tid; i < B_ * H_; i += 256) sh2[i] = enc_h[i];
  __syncthreads();
  const int vl = tid & 63, wid = tid >> 6;
  const int g = q * 64 + vl;
  const float4* wrow = (const float4*)(Wa_w + (size_t)g * H_);
  const float wb = Wa_b[g];
#pragma unroll 1
  for (int bb = 0; bb < 8; ++bb) {
    const int b = wid * 8 + bb;
    const float4* x4 = (const float4*)(sh2 + b * H_);
    float acc = wb;
    for (int k = 0; k < H_ / 4; ++k) {
      const float4 w = wrow[k], x = x4[k];
      acc += w.x * x.x + w.y * x.y + w.z * x.z + w.w * x.w;
    }
    g_wq[b * H_ + g] = acc;
    g_hT[0][g * 32 + b] = sh2[b * H_ + g];
  }
}

// ---------------- per step: attention only (weights untouched). grid 32 x 256
__global__ void k_attn(const int* __restrict__ tgt, const float* __restrict__ emb_tab,
                       const float* __restrict__ Va_w, const float* __restrict__ Va_b,
                       const float* __restrict__ keys, float* __restrict__ out, int t) {
  __shared__ float swq[H_], sva[H_], semb[H_], sscore[64], sw[64];
  const int b = blockIdx.x, g = threadIdx.x;
  const int lane = g & 63, wid = g >> 6;
  swq[g] = g_wq[b * H_ + g];
  sva[g] = Va_w[g];
  const int tok = (t == 0) ? SOS : tgt[b * T_ + (t - 1)];
  semb[g] = emb_tab[(size_t)tok * H_ + g];
  __syncthreads();

  const float vab = Va_b[0];
  for (int s = wid; s < S_; s += 4) {
    const float* uarow = g_ua + (size_t)(b * S_ + s) * H_;
    float acc = 0.f;
#pragma unroll
    for (int i = 0; i < 4; ++i) {
      const int gg = lane + i * 64;
      acc += tanhf(swq[gg] + uarow[gg]) * sva[gg];
    }
    for (int off = 32; off > 0; off >>= 1) acc += __shfl_down(acc, off);
    if (lane == 0) sscore[s] = acc + vab;
  }
  __syncthreads();

  if (g < 64) {
    const float v = (g < S_) ? sscore[g] : -INFINITY;
    float m = v;
    for (int off = 32; off > 0; off >>= 1) m = fmaxf(m, __shfl_xor(m, off));
    const float e = (g < S_) ? expf(v - m) : 0.f;
    float ssum = e;
    for (int off = 32; off > 0; off >>= 1) ssum += __shfl_xor(ssum, off);
    const float w = e / ssum;
    if (g < S_) {
      sw[g] = w;
      out[(size_t)B_ * T_ * V_ + (size_t)B_ * H_ + (size_t)(b * T_ + t) * S_ + g] = w;
    }
  }
  __syncthreads();

  float cx = 0.f;
  for (int s = 0; s < S_; ++s) cx += sw[s] * keys[(size_t)(b * S_ + s) * H_ + g];
  g_xT[g * 32 + b] = f2bf(semb[g]);
  g_xT[(H_ + g) * 32 + b] = f2bf(cx);
}

// ---------------- per step: GRU. grid 64 x 256; block = 4 units x 32 b x splitK2
__global__ void k_gru(const float* __restrict__ b_ih, const float* __restrict__ b_hh,
                      float* __restrict__ out, int t) {
  __shared__ ushort_t sxT[2 * H_ * B_];   // 32 KB bf16 x transposed
  __shared__ ushort_t shT[H_ * B_];       // 16 KB bf16 h transposed
  __shared__ float sred[4 * 3 * 2 * 32 * 2];  // 6 KB partials
  const int tid = threadIdx.x, bid = blockIdx.x;
  const int cur = t & 1, nxt = cur ^ 1;
  // stage xT (bf16 copy) and hT (f32 -> bf16)
  {
    const ushort8* src = (const ushort8*)g_xT;
    ushort8* dst = (ushort8*)sxT;
    for (int i = tid; i < 2 * H_ * B_ / 8; i += 256) dst[i] = src[i];
    const float4* hs = (const float4*)g_hT[cur];
    for (int i = tid; i < H_ * B_ / 4; i += 256) {
      const float4 v = hs[i];
      shT[i * 4 + 0] = f2bf(v.x); shT[i * 4 + 1] = f2bf(v.y);
      shT[i * 4 + 2] = f2bf(v.z); shT[i * 4 + 3] = f2bf(v.w);
    }
  }
  __syncthreads();

  const int b = tid & 31, kq = (tid >> 5) & 1, ul = tid >> 6;
  const int ug = bid * 4 + ul;
#pragma unroll
  for (int gate = 0; gate < 3; ++gate) {
    const int row = gate * H_ + ug;
    float acc = 0.f;
    const ushort8* wb = (const ushort8*)(g_wihbf + (size_t)row * (2 * H_) + kq * 256);
    for (int i8 = 0; i8 < 32; ++i8) {
      const ushort8 w8 = wb[i8];
      const int kbase = kq * 256 + i8 * 8;
#pragma unroll
      for (int j = 0; j < 8; ++j)
        acc += bf2f(w8[j]) * bf2f(sxT[(kbase + j) * 32 + b]);
    }
    float acc2 = 0.f;
    const ushort8* wb2 = (const ushort8*)(g_whhbf + (size_t)row * H_ + kq * 128);
    for (int i8 = 0; i8 < 16; ++i8) {
      const ushort8 w8 = wb2[i8];
      const int kbase = kq * 128 + i8 * 8;
#pragma unroll
      for (int j = 0; j < 8; ++j)
        acc2 += bf2f(w8[j]) * bf2f(shT[(kbase + j) * 32 + b]);
    }
    sred[(((ul * 3 + gate) * 2 + kq) * 32 + b) * 2 + 0] = acc;
    sred[(((ul * 3 + gate) * 2 + kq) * 32 + b) * 2 + 1] = acc2;
  }
  __syncthreads();

  if (tid < 128) {
    const int b2 = tid & 31, u2 = tid >> 5;
    const int ug2 = bid * 4 + u2;
    float gi[3], gh[3];
#pragma unroll
    for (int gate = 0; gate < 3; ++gate) {
      const int base = ((u2 * 3 + gate) * 2) * 32;
      gi[gate] = sred[(base + b2) * 2 + 0] + sred[(base + 32 + b2) * 2 + 0]
               + b_ih[gate * H_ + ug2];
      gh[gate] = sred[(base + b2) * 2 + 1] + sred[(base + 32 + b2) * 2 + 1]
               + b_hh[gate * H_ + ug2];
    }
    const float r = 1.f / (1.f + expf(-(gi[0] + gh[0])));
    const float z = 1.f / (1.f + expf(-(gi[1] + gh[1])));
    const float n = tanhf(gi[2] + r * gh[2]);
    const float hold = g_hT[cur][ug2 * 32 + b2];
    const float h2 = (1.f - z) * n + z * hold;
    g_h[b2 * H_ + ug2] = h2;
    g_hT[nxt][ug2 * 32 + b2] = h2;
    if (t == T_ - 1) out[(size_t)B_ * T_ * V_ + b2 * H_ + ug2] = h2;
  }
}

// ---------------- per step: logits (bf16 weights) + wa_q tail. grid 790 x 256
__global__ void k_logits(const float* __restrict__ out_b, const float* __restrict__ Wa_w,
                         const float* __restrict__ Wa_b, float* __restrict__ out, int t) {
  __shared__ float sh2[B_ * H_];
  const int tid = threadIdx.x, bid = blockIdx.x;
  for (int i = tid; i < B_ * H_; i += 256) sh2[i] = g_h[i];
  __syncthreads();
  const int vl = tid & 63, wid = tid >> 6;
  if (bid < NCH) {
    const int v = bid * 64 + vl;
    const bool valid = (v < V_);
    float acc[8];
    const float base = valid ? out_b[v] : 0.f;
#pragma unroll
    for (int bb = 0; bb < 8; ++bb) acc[bb] = valid ? base : -INFINITY;
    if (valid) {
      const ushort8* wrow = (const ushort8*)(g_wbf + (size_t)v * H_);
      const float4* sh4 = (const float4*)sh2;
      for (int k8 = 0; k8 < 32; ++k8) {
        const ushort8 w = wrow[k8];
        float wf[8];
#pragma unroll
        for (int j = 0; j < 8; ++j) wf[j] = bf2f(w[j]);
#pragma unroll
        for (int bb = 0; bb < 8; ++bb) {
          const int bidx = wid * 8 + bb;
          const float4 a = sh4[bidx * 64 + k8 * 2];
          const float4 c = sh4[bidx * 64 + k8 * 2 + 1];
          acc[bb] += wf[0] * a.x + wf[1] * a.y + wf[2] * a.z + wf[3] * a.w
                   + wf[4] * c.x + wf[5] * c.y + wf[6] * c.z + wf[7] * c.w;
        }
      }
#pragma unroll
      for (int bb = 0; bb < 8; ++bb)
        out[((size_t)((wid * 8 + bb) * T_ + t)) * V_ + v] = acc[bb];
    }
#pragma unroll
    for (int bb = 0; bb < 8; ++bb) {
      float m = acc[bb];
      for (int off = 32; off > 0; off >>= 1) m = fmaxf(m, __shfl_xor(m, off));
      const float e = valid ? expf(acc[bb] - m) : 0.f;
      float s = e;
      for (int off = 32; off > 0; off >>= 1) s += __shfl_xor(s, off);
      if (vl == 0) {
        g_pmax[(size_t)(wid * 8 + bb) * NCH + bid] = m;
        g_psum[(size_t)(wid * 8 + bb) * NCH + bid] = s;
      }
    }
  } else {
    // tail: wa_q for next step from h2 staged in sh2
    const int q = bid - NCH;
    const int g = q * 64 + vl;
    const float4* wrow = (const float4*)(Wa_w + (size_t)g * H_);
    const float wb = Wa_b[g];
#pragma unroll 1
    for (int bb = 0; bb < 8; ++bb) {
      const int b = wid * 8 + bb;
      const float4* x4 = (const float4*)(sh2 + b * H_);
      float acc = wb;
      for (int k = 0; k < H_ / 4; ++k) {
        const float4 w = wrow[k], x = x4[k];
        acc += w.x * x.x + w.y * x.y + w.z * x.z + w.w * x.w;
      }
      g_wq[b * H_ + g] = acc;
    }
  }
}

// ---------------- per step: combine partials -> lse, rewrite log-softmax in place
__global__ void k_write(float* __restrict__ out, int t) {
  __shared__ float red[4];
  const int b = blockIdx.y;
  const int tid = threadIdx.x;
  float m = -INFINITY;
  for (int i = tid; i < NCH; i += 256) m = fmaxf(m, g_pmax[(size_t)b * NCH + i]);
  for (int off = 32; off > 0; off >>= 1) m = fmaxf(m, __shfl_xor(m, off));
  if ((tid & 63) == 0) red[tid >> 6] = m;
  __syncthreads();
  m = fmaxf(fmaxf(red[0], red[1]), fmaxf(red[2], red[3]));
  __syncthreads();
  float s = 0.f;
  for (int i = tid; i < NCH; i += 256)
    s += g_psum[(size_t)b * NCH + i] * expf(g_pmax[(size_t)b * NCH + i] - m);
  for (int off = 32; off > 0; off >>= 1) s += __shfl_xor(s, off);
  if ((tid & 63) == 0) red[tid >> 6] = s;
  __syncthreads();
  s = red[0] + red[1] + red[2] + red[3];
  float lse = m + logf(s);
  if (!isfinite(lse)) lse = 0.f;
  const size_t obase = ((size_t)b * T_ + t) * (size_t)V_;
  const int vbase = blockIdx.x * 2048;
#pragma unroll
  for (int j = 0; j < 8; ++j) {
    const int v = vbase + j * 256 + tid;
    if (v < V_) out[obase + v] = out[obase + v] - lse;
  }
}

extern "C" void kernel_launch(void* const* d_in, const int* in_sizes, int n_in,
                              void* d_out, int out_size, void* d_ws, size_t ws_size,
                              hipStream_t stream) {
  const float* enc_h  = (const float*)d_in[0];
  const float* keys   = (const float*)d_in[1];
  const int*   tgt    = (const int*)d_in[2];
  const float* emb    = (const float*)d_in[3];
  const float* Wa_w   = (const float*)d_in[4];
  const float* Wa_b   = (const float*)d_in[5];
  const float* Ua_w   = (const float*)d_in[6];
  const float* Ua_b   = (const float*)d_in[7];
  const float* Va_w   = (const float*)d_in[8];
  const float* Va_b   = (const float*)d_in[9];
  const float* W_ih   = (const float*)d_in[10];
  const float* b_ih   = (const float*)d_in[11];
  const float* W_hh   = (const float*)d_in[12];
  const float* b_hh   = (const float*)d_in[13];
  const float* out_w  = (const float*)d_in[14];
  const float* out_b  = (const float*)d_in[15];
  float* out = (float*)d_out;
  (void)d_ws; (void)ws_size;

  hipLaunchKernelGGL(k_prep, dim3(2048), dim3(256), 0, stream, out_w, W_ih, W_hh);
  hipLaunchKernelGGL(k_ua, dim3(B_ * S_), dim3(H_), 0, stream, keys, Ua_w, Ua_b);
  hipLaunchKernelGGL(k_init, dim3(4), dim3(256), 0, stream, enc_h, Wa_w, Wa_b);
  for (int t = 0; t < T_; ++t) {
    hipLaunchKernelGGL(k_attn, dim3(B_), dim3(H_), 0, stream,
                       tgt, emb, Va_w, Va_b, keys, out, t);
    hipLaunchKernelGGL(k_gru, dim3(64), dim3(256), 0, stream, b_ih, b_hh, out, t);
    hipLaunchKernelGGL(k_logits, dim3(NCH + 4), dim3(256), 0, stream,
                       out_b, Wa_w, Wa_b, out, t);
    hipLaunchKernelGGL(k_write, dim3(25, B_), dim3(256), 0, stream, out, t);
  }
}

// Round 6
// 2758.806 us; speedup vs baseline: 2.0906x; 1.2185x over previous
//
#include <hip/hip_runtime.h>
#include <math.h>

#define B_ 32
#define S_ 50
#define H_ 256
#define T_ 25
#define V_ 50257
#define NCH 786   /* ceil(V/64) */
#define NROW (B_ * T_)
#define SOS 0

typedef unsigned short ushort_t;
typedef __attribute__((ext_vector_type(8))) unsigned short ushort8;

// ---- static device scratch (loader-allocated; fully rewritten each call)
__device__ float    g_ua[B_ * S_ * H_];        // 1.6 MB f32 ua_keys
__device__ float    g_hall[T_ * B_ * H_];      // h2 for all steps, [t][b][g]
__device__ ushort_t g_wbf[(size_t)V_ * H_];    // out_w bf16
__device__ ushort_t g_wihbf[3 * H_ * 2 * H_];  // W_ih bf16
__device__ ushort_t g_whhbf[3 * H_ * H_];      // W_hh bf16
__device__ ushort_t g_wabf[H_ * H_];           // Wa_w bf16
__device__ float    g_pmax[NROW * NCH];        // 2.5 MB
__device__ float    g_psum[NROW * NCH];        // 2.5 MB

__device__ __forceinline__ float bf2f(ushort_t h) {
  union { unsigned int u; float f; } c; c.u = ((unsigned int)h) << 16; return c.f;
}
__device__ __forceinline__ ushort_t f2bf(float f) {
  union { float f; unsigned int u; } c; c.f = f;
  unsigned int u = c.u;
  return (ushort_t)((u + 0x7FFFu + ((u >> 16) & 1u)) >> 16);
}

// ---------------- one launch: ua GEMM (blocks 0..1599) + bf16 weight converts
__global__ void k_setup(const float* __restrict__ keys, const float* __restrict__ Ua_w,
                        const float* __restrict__ Ua_b, const float* __restrict__ out_w,
                        const float* __restrict__ W_ih, const float* __restrict__ W_hh,
                        const float* __restrict__ Wa_w) {
  const int bid = blockIdx.x, tid = threadIdx.x;
  if (bid < B_ * S_) {
    __shared__ float sk[H_];
    sk[tid] = keys[bid * H_ + tid];
    __syncthreads();
    float acc = Ua_b[tid];
    const float4* wrow = (const float4*)(Ua_w + (size_t)tid * H_);
    const float4* sk4 = (const float4*)sk;
    for (int k = 0; k < H_ / 4; ++k) {
      const float4 w = wrow[k], x = sk4[k];
      acc += w.x * x.x + w.y * x.y + w.z * x.z + w.w * x.w;
    }
    g_ua[(size_t)bid * H_ + tid] = acc;
  } else {
    const int cb = bid - B_ * S_;
    const size_t i0 = (size_t)cb * 256 + tid;
    const size_t stride = 2048u * 256u;
    for (size_t i = i0; i < (size_t)V_ * H_; i += stride) g_wbf[i] = f2bf(out_w[i]);
    for (size_t i = i0; i < 3 * H_ * 2 * H_; i += stride) g_wihbf[i] = f2bf(W_ih[i]);
    for (size_t i = i0; i < 3 * H_ * H_; i += stride) g_whhbf[i] = f2bf(W_hh[i]);
    for (size_t i = i0; i < H_ * H_; i += stride) g_wabf[i] = f2bf(Wa_w[i]);
  }
}

// ---------------- ONE launch for the whole 25-step recurrence. 32 blocks, block=batch row.
__global__ void __launch_bounds__(256, 1)
k_recur(const float* __restrict__ enc_h, const int* __restrict__ tgt,
        const float* __restrict__ emb_tab, const float* __restrict__ Wa_b,
        const float* __restrict__ Va_w, const float* __restrict__ Va_b,
        const float* __restrict__ keys, const float* __restrict__ b_ih,
        const float* __restrict__ b_hh, float* __restrict__ out) {
  __shared__ float s_ua[S_ * H_];    // 50 KB, staged once
  __shared__ float s_keys[S_ * H_];  // 50 KB, staged once
  __shared__ float s_h[H_];
  __shared__ float s_x[2 * H_];      // [emb, ctx]
  __shared__ float s_wq[H_];
  __shared__ float s_va[H_];
  __shared__ float s_bih[3 * H_], s_bhh[3 * H_];
  __shared__ float s_score[64], s_w[64];
  const int b = blockIdx.x, g = threadIdx.x;
  const int lane = g & 63, wid = g >> 6;

  // one-time staging
  for (int i = g; i < S_ * H_; i += 256) {
    s_ua[i] = g_ua[(size_t)b * S_ * H_ + i];
    s_keys[i] = keys[(size_t)b * S_ * H_ + i];
  }
  s_h[g] = enc_h[b * H_ + g];
  s_va[g] = Va_w[g];
#pragma unroll
  for (int j = 0; j < 3; ++j) {
    s_bih[j * H_ + g] = b_ih[j * H_ + g];
    s_bhh[j * H_ + g] = b_hh[j * H_ + g];
  }
  const float wab = Wa_b[g];
  const float vab = Va_b[0];
  __syncthreads();

  for (int t = 0; t < T_; ++t) {
    // wa_q[g] = h . Wa_w[g,:] + Wa_b[g]   (bf16 weights)
    {
      float acc = wab;
      const ushort8* wrow = (const ushort8*)(g_wabf + (size_t)g * H_);
      for (int k8 = 0; k8 < 32; ++k8) {
        const ushort8 w = wrow[k8];
#pragma unroll
        for (int j = 0; j < 8; ++j) acc += bf2f(w[j]) * s_h[k8 * 8 + j];
      }
      s_wq[g] = acc;
    }
    // emb
    const int tok = (t == 0) ? SOS : tgt[b * T_ + (t - 1)];
    s_x[g] = emb_tab[(size_t)tok * H_ + g];
    __syncthreads();

    // scores[s] = sum_g tanh(wq+ua)*va + vab ; waves split s
    for (int s = wid; s < S_; s += 4) {
      const float* uarow = s_ua + s * H_;
      float acc = 0.f;
#pragma unroll
      for (int i = 0; i < 4; ++i) {
        const int gg = lane + i * 64;
        acc += tanhf(s_wq[gg] + uarow[gg]) * s_va[gg];
      }
      for (int off = 32; off > 0; off >>= 1) acc += __shfl_down(acc, off);
      if (lane == 0) s_score[s] = acc + vab;
    }
    __syncthreads();

    // softmax over S on wave 0; write attention output
    if (g < 64) {
      const float v = (g < S_) ? s_score[g] : -INFINITY;
      float m = v;
      for (int off = 32; off > 0; off >>= 1) m = fmaxf(m, __shfl_xor(m, off));
      const float e = (g < S_) ? expf(v - m) : 0.f;
      float ssum = e;
      for (int off = 32; off > 0; off >>= 1) ssum += __shfl_xor(ssum, off);
      const float w = e / ssum;
      if (g < S_) {
        s_w[g] = w;
        out[(size_t)B_ * T_ * V_ + (size_t)B_ * H_ + (size_t)(b * T_ + t) * S_ + g] = w;
      }
    }
    __syncthreads();

    // ctx
    {
      float cx = 0.f;
      for (int s = 0; s < S_; ++s) cx += s_w[s] * s_keys[s * H_ + g];
      s_x[H_ + g] = cx;
    }
    __syncthreads();

    // GRU: thread g owns unit g, all 3 gates
    float gi[3], gh[3];
#pragma unroll
    for (int gate = 0; gate < 3; ++gate) {
      const int row = gate * H_ + g;
      float acc = s_bih[row];
      const ushort8* wb = (const ushort8*)(g_wihbf + (size_t)row * (2 * H_));
      for (int k8 = 0; k8 < 64; ++k8) {
        const ushort8 w = wb[k8];
#pragma unroll
        for (int j = 0; j < 8; ++j) acc += bf2f(w[j]) * s_x[k8 * 8 + j];
      }
      gi[gate] = acc;
      float acc2 = s_bhh[row];
      const ushort8* wb2 = (const ushort8*)(g_whhbf + (size_t)row * H_);
      for (int k8 = 0; k8 < 32; ++k8) {
        const ushort8 w = wb2[k8];
#pragma unroll
        for (int j = 0; j < 8; ++j) acc2 += bf2f(w[j]) * s_h[k8 * 8 + j];
      }
      gh[gate] = acc2;
    }
    const float r = 1.f / (1.f + expf(-(gi[0] + gh[0])));
    const float z = 1.f / (1.f + expf(-(gi[1] + gh[1])));
    const float n = tanhf(gi[2] + r * gh[2]);
    const float h2 = (1.f - z) * n + z * s_h[g];
    g_hall[((size_t)t * B_ + b) * H_ + g] = h2;
    if (t == T_ - 1) out[(size_t)B_ * T_ * V_ + b * H_ + g] = h2;
    __syncthreads();
    s_h[g] = h2;
    __syncthreads();
  }
}

// ---------------- one launch: logits for ALL (t,b) rows. grid (786, 25)
__global__ void k_logits(const float* __restrict__ out_b, float* __restrict__ out) {
  __shared__ float sh2[B_ * H_];
  const int tid = threadIdx.x, chunk = blockIdx.x, t = blockIdx.y;
  for (int i = tid; i < B_ * H_; i += 256) sh2[i] = g_hall[(size_t)t * B_ * H_ + i];
  __syncthreads();
  const int vl = tid & 63, wid = tid >> 6;
  const int v = chunk * 64 + vl;
  const bool valid = (v < V_);
  float acc[8];
  const float base = valid ? out_b[v] : 0.f;
#pragma unroll
  for (int bb = 0; bb < 8; ++bb) acc[bb] = valid ? base : -INFINITY;
  if (valid) {
    const ushort8* wrow = (const ushort8*)(g_wbf + (size_t)v * H_);
    const float4* sh4 = (const float4*)sh2;
    for (int k8 = 0; k8 < 32; ++k8) {
      const ushort8 w = wrow[k8];
      float wf[8];
#pragma unroll
      for (int j = 0; j < 8; ++j) wf[j] = bf2f(w[j]);
#pragma unroll
      for (int bb = 0; bb < 8; ++bb) {
        const int bidx = wid * 8 + bb;
        const float4 a = sh4[bidx * 64 + k8 * 2];
        const float4 c = sh4[bidx * 64 + k8 * 2 + 1];
        acc[bb] += wf[0] * a.x + wf[1] * a.y + wf[2] * a.z + wf[3] * a.w
                 + wf[4] * c.x + wf[5] * c.y + wf[6] * c.z + wf[7] * c.w;
      }
    }
#pragma unroll
    for (int bb = 0; bb < 8; ++bb) {
      const int r = (wid * 8 + bb) * T_ + t;
      out[(size_t)r * V_ + v] = acc[bb];
    }
  }
#pragma unroll
  for (int bb = 0; bb < 8; ++bb) {
    float m = acc[bb];
    for (int off = 32; off > 0; off >>= 1) m = fmaxf(m, __shfl_xor(m, off));
    const float e = valid ? expf(acc[bb] - m) : 0.f;
    float s = e;
    for (int off = 32; off > 0; off >>= 1) s += __shfl_xor(s, off);
    if (vl == 0) {
      const int r = (wid * 8 + bb) * T_ + t;
      g_pmax[(size_t)r * NCH + chunk] = m;
      g_psum[(size_t)r * NCH + chunk] = s;
    }
  }
}

// ---------------- one launch: lse + in-place log-softmax. grid (25, 800)
__global__ void k_write(float* __restrict__ out) {
  __shared__ float red[4];
  const int r = blockIdx.y;   // r = b*T + t
  const int tid = threadIdx.x;
  float m = -INFINITY;
  for (int i = tid; i < NCH; i += 256) m = fmaxf(m, g_pmax[(size_t)r * NCH + i]);
  for (int off = 32; off > 0; off >>= 1) m = fmaxf(m, __shfl_xor(m, off));
  if ((tid & 63) == 0) red[tid >> 6] = m;
  __syncthreads();
  m = fmaxf(fmaxf(red[0], red[1]), fmaxf(red[2], red[3]));
  __syncthreads();
  float s = 0.f;
  for (int i = tid; i < NCH; i += 256)
    s += g_psum[(size_t)r * NCH + i] * expf(g_pmax[(size_t)r * NCH + i] - m);
  for (int off = 32; off > 0; off >>= 1) s += __shfl_xor(s, off);
  if ((tid & 63) == 0) red[tid >> 6] = s;
  __syncthreads();
  s = red[0] + red[1] + red[2] + red[3];
  float lse = m + logf(s);
  if (!isfinite(lse)) lse = 0.f;
  const size_t obase = (size_t)r * V_;
  const int vbase = blockIdx.x * 2048;
#pragma unroll
  for (int j = 0; j < 8; ++j) {
    const int v = vbase + j * 256 + tid;
    if (v < V_) out[obase + v] = out[obase + v] - lse;
  }
}

extern "C" void kernel_launch(void* const* d_in, const int* in_sizes, int n_in,
                              void* d_out, int out_size, void* d_ws, size_t ws_size,
                              hipStream_t stream) {
  const float* enc_h  = (const float*)d_in[0];
  const float* keys   = (const float*)d_in[1];
  const int*   tgt    = (const int*)d_in[2];
  const float* emb    = (const float*)d_in[3];
  const float* Wa_w   = (const float*)d_in[4];
  const float* Wa_b   = (const float*)d_in[5];
  const float* Ua_w   = (const float*)d_in[6];
  const float* Ua_b   = (const float*)d_in[7];
  const float* Va_w   = (const float*)d_in[8];
  const float* Va_b   = (const float*)d_in[9];
  const float* b_ih   = (const float*)d_in[11];
  const float* b_hh   = (const float*)d_in[13];
  const float* out_w  = (const float*)d_in[14];
  const float* out_b  = (const float*)d_in[15];
  const float* W_ih   = (const float*)d_in[10];
  const float* W_hh   = (const float*)d_in[12];
  float* out = (float*)d_out;
  (void)d_ws; (void)ws_size;

  hipLaunchKernelGGL(k_setup, dim3(B_ * S_ + 2048), dim3(256), 0, stream,
                     keys, Ua_w, Ua_b, out_w, W_ih, W_hh, Wa_w);
  hipLaunchKernelGGL(k_recur, dim3(B_), dim3(256), 0, stream,
                     enc_h, tgt, emb, Wa_b, Va_w, Va_b, keys, b_ih, b_hh, out);
  hipLaunchKernelGGL(k_logits, dim3(NCH, T_), dim3(256), 0, stream, out_b, out);
  hipLaunchKernelGGL(k_write, dim3(25, NROW), dim3(256), 0, stream, out);
}

// Round 7
// 1894.859 us; speedup vs baseline: 3.0438x; 1.4559x over previous
//
#include <hip/hip_runtime.h>
#include <math.h>

#define B_ 32
#define S_ 50
#define H_ 256
#define T_ 25
#define V_ 50257
#define NCH 786   /* ceil(V/64) */
#define NROW (B_ * T_)
#define NWROW 1792  /* 256 Wa + 768 W_hh + 768 W_ih[:,256:] */
#define SOS 0

typedef unsigned short ushort_t;
typedef __attribute__((ext_vector_type(8))) unsigned short ushort8;

// ---- static device scratch (loader-allocated; fully rewritten each call)
__device__ float    g_ua[B_ * S_ * H_];        // ua_keys + Wa_b folded in
__device__ float    g_hall[T_ * B_ * H_];      // h2 for all steps, [t][b][g]
__device__ float    g_gie[T_ * B_ * 3 * H_];   // W_ih[:,:256].emb + b_ih, [t][b][768]
__device__ ushort_t g_wbf[(size_t)V_ * H_];    // out_w bf16
__device__ ushort_t g_wcat[NWROW * H_];        // packed bf16 [Wa; W_hh; W_ihc], K=256
__device__ float    g_pmax[NROW * NCH];
__device__ float    g_psum[NROW * NCH];

__device__ __forceinline__ float bf2f(ushort_t h) {
  union { unsigned int u; float f; } c; c.u = ((unsigned int)h) << 16; return c.f;
}
__device__ __forceinline__ ushort_t f2bf(float f) {
  union { float f; unsigned int u; } c; c.f = f;
  unsigned int u = c.u;
  return (ushort_t)((u + 0x7FFFu + ((u >> 16) & 1u)) >> 16);
}

// ---------------- one launch: ua GEMM (blocks 0..1599) + bf16 packs (blocks 1600..)
__global__ void k_setup(const float* __restrict__ keys, const float* __restrict__ Ua_w,
                        const float* __restrict__ Ua_b, const float* __restrict__ Wa_b,
                        const float* __restrict__ out_w, const float* __restrict__ W_ih,
                        const float* __restrict__ W_hh, const float* __restrict__ Wa_w) {
  const int bid = blockIdx.x, tid = threadIdx.x;
  if (bid < B_ * S_) {
    __shared__ float sk[H_];
    sk[tid] = keys[bid * H_ + tid];
    __syncthreads();
    float acc = Ua_b[tid] + Wa_b[tid];   // fold Wa_b into ua
    const float4* wrow = (const float4*)(Ua_w + (size_t)tid * H_);
    const float4* sk4 = (const float4*)sk;
    for (int k = 0; k < H_ / 4; ++k) {
      const float4 w = wrow[k], x = sk4[k];
      acc += w.x * x.x + w.y * x.y + w.z * x.z + w.w * x.w;
    }
    g_ua[(size_t)bid * H_ + tid] = acc;
  } else {
    const int cb = bid - B_ * S_;
    const size_t i0 = (size_t)cb * 256 + tid;
    const size_t stride = 2048u * 256u;
    for (size_t i = i0; i < (size_t)V_ * H_; i += stride) g_wbf[i] = f2bf(out_w[i]);
    for (size_t i = i0; i < (size_t)NWROW * H_; i += stride) {
      const int r = (int)(i >> 8), k = (int)(i & 255);
      float v;
      if (r < 256)       v = Wa_w[r * H_ + k];
      else if (r < 1024) v = W_hh[(r - 256) * H_ + k];
      else               v = W_ih[(size_t)(r - 1024) * (2 * H_) + H_ + k];
      g_wcat[i] = f2bf(v);
    }
  }
}

// ---------------- one launch: gie[t][b][j] = emb(tok[t,b]) . W_ih[j,:256] + b_ih[j]
__global__ void k_gie(const int* __restrict__ tgt, const float* __restrict__ emb_tab,
                      const float* __restrict__ W_ih, const float* __restrict__ b_ih) {
  __shared__ float semb[B_ * H_];
  const int tid = threadIdx.x, chunk = blockIdx.x, t = blockIdx.y;
  for (int i = tid; i < B_ * H_; i += 256) {
    const int b = i >> 8, g = i & 255;
    const int tok = (t == 0) ? SOS : tgt[b * T_ + (t - 1)];
    semb[i] = emb_tab[(size_t)tok * H_ + g];
  }
  __syncthreads();
  const int vl = tid & 63, wd = tid >> 6;
  const int j = chunk * 64 + vl;          // unit in [0,768)
  const float4* wrow = (const float4*)(W_ih + (size_t)j * (2 * H_));  // first 256 cols
  const float4* se4 = (const float4*)semb;
  float acc[8];
  const float base = b_ih[j];
#pragma unroll
  for (int bb = 0; bb < 8; ++bb) acc[bb] = base;
  for (int k4 = 0; k4 < 64; ++k4) {
    const float4 w = wrow[k4];
#pragma unroll
    for (int bb = 0; bb < 8; ++bb) {
      const float4 x = se4[(wd * 8 + bb) * 64 + k4];
      acc[bb] += w.x * x.x + w.y * x.y + w.z * x.z + w.w * x.w;
    }
  }
#pragma unroll
  for (int bb = 0; bb < 8; ++bb)
    g_gie[((size_t)t * B_ + (wd * 8 + bb)) * (3 * H_) + j] = acc[bb];
}

// ---------------- ONE launch, whole recurrence. 32 blocks; coalesced lane-split matvecs.
__global__ void __launch_bounds__(256, 1)
k_recur(const float* __restrict__ enc_h, const float* __restrict__ Va_w,
        const float* __restrict__ Va_b, const float* __restrict__ keys,
        const float* __restrict__ b_hh, float* __restrict__ out) {
  __shared__ float s_ua[S_ * H_];    // 50 KB
  __shared__ float s_keys[S_ * H_];  // 50 KB
  __shared__ float s_res[NWROW];     // 7 KB: [0,256)=Wa.h, [256,1024)=W_hh.h, [1024,1792)=W_ihc.ctx
  __shared__ float s_h[H_];
  __shared__ float s_ctx[H_];
  __shared__ float s_va[H_];
  __shared__ float s_score[64], s_w[64];
  const int b = blockIdx.x, tid = threadIdx.x;
  const int lane = tid & 63, wid = tid >> 6;
  const int sub = lane & 15;                 // lane within 16-group
  const int grp = (wid << 2) | (lane >> 4);  // 0..15 row-slot

  for (int i = tid; i < S_ * H_; i += 256) {
    s_ua[i] = g_ua[(size_t)b * S_ * H_ + i];
    s_keys[i] = keys[(size_t)b * S_ * H_ + i];
  }
  s_h[tid] = enc_h[b * H_ + tid];
  s_va[tid] = Va_w[tid];
  const float vab = Va_b[0];
  const float bhh0 = b_hh[tid], bhh1 = b_hh[H_ + tid], bhh2 = b_hh[2 * H_ + tid];
  __syncthreads();

  for (int t = 0; t < T_; ++t) {
    // ---- sweep rows [0,1024): vec = h. 16 lanes per row, 2x256B coalesced segs/row.
#pragma unroll 2
    for (int it = 0; it < 64; ++it) {
      const int row = it * 16 + grp;
      const ushort8* wr = (const ushort8*)(g_wcat + (size_t)row * H_);
      const ushort8 w0 = wr[sub], w1 = wr[16 + sub];
      const float* v0 = s_h + sub * 8;
      const float* v1 = s_h + 128 + sub * 8;
      float a0 = 0.f, a1 = 0.f;
#pragma unroll
      for (int j = 0; j < 8; ++j) { a0 += bf2f(w0[j]) * v0[j]; a1 += bf2f(w1[j]) * v1[j]; }
      float a = a0 + a1;
      a += __shfl_xor(a, 8); a += __shfl_xor(a, 4);
      a += __shfl_xor(a, 2); a += __shfl_xor(a, 1);
      if (sub == 0) s_res[row] = a;
    }
    __syncthreads();

    // ---- attention scores: tanh(wq[g]+ua[s,g])*va  (Wa_b folded into ua)
    for (int s = wid; s < S_; s += 4) {
      const float* uarow = s_ua + s * H_;
      float acc = 0.f;
#pragma unroll
      for (int i = 0; i < 4; ++i) {
        const int gg = lane + i * 64;
        acc += tanhf(s_res[gg] + uarow[gg]) * s_va[gg];
      }
      for (int off = 32; off > 0; off >>= 1) acc += __shfl_xor(acc, off);
      if (lane == 0) s_score[s] = acc + vab;
    }
    __syncthreads();

    // ---- softmax over S on wave 0; write attention output
    if (tid < 64) {
      const float v = (tid < S_) ? s_score[tid] : -INFINITY;
      float m = v;
      for (int off = 32; off > 0; off >>= 1) m = fmaxf(m, __shfl_xor(m, off));
      const float e = (tid < S_) ? expf(v - m) : 0.f;
      float ssum = e;
      for (int off = 32; off > 0; off >>= 1) ssum += __shfl_xor(ssum, off);
      const float w = e / ssum;
      if (tid < S_) {
        s_w[tid] = w;
        out[(size_t)B_ * T_ * V_ + (size_t)B_ * H_ + (size_t)(b * T_ + t) * S_ + tid] = w;
      }
    }
    __syncthreads();

    // ---- ctx
    {
      float cx = 0.f;
      for (int s = 0; s < S_; ++s) cx += s_w[s] * s_keys[s * H_ + tid];
      s_ctx[tid] = cx;
    }
    __syncthreads();

    // ---- sweep rows [1024,1792): vec = ctx
#pragma unroll 2
    for (int it = 0; it < 48; ++it) {
      const int row = 1024 + it * 16 + grp;
      const ushort8* wr = (const ushort8*)(g_wcat + (size_t)row * H_);
      const ushort8 w0 = wr[sub], w1 = wr[16 + sub];
      const float* v0 = s_ctx + sub * 8;
      const float* v1 = s_ctx + 128 + sub * 8;
      float a0 = 0.f, a1 = 0.f;
#pragma unroll
      for (int j = 0; j < 8; ++j) { a0 += bf2f(w0[j]) * v0[j]; a1 += bf2f(w1[j]) * v1[j]; }
      float a = a0 + a1;
      a += __shfl_xor(a, 8); a += __shfl_xor(a, 4);
      a += __shfl_xor(a, 2); a += __shfl_xor(a, 1);
      if (sub == 0) s_res[row] = a;
    }
    __syncthreads();

    // ---- GRU finish: thread owns unit g=tid
    const float* gie = g_gie + ((size_t)t * B_ + b) * (3 * H_);
    const float gi0 = gie[tid] + s_res[1024 + tid];
    const float gi1 = gie[H_ + tid] + s_res[1024 + H_ + tid];
    const float gi2 = gie[2 * H_ + tid] + s_res[1024 + 2 * H_ + tid];
    const float gh0 = s_res[256 + tid] + bhh0;
    const float gh1 = s_res[256 + H_ + tid] + bhh1;
    const float gh2 = s_res[256 + 2 * H_ + tid] + bhh2;
    const float r = 1.f / (1.f + expf(-(gi0 + gh0)));
    const float z = 1.f / (1.f + expf(-(gi1 + gh1)));
    const float n = tanhf(gi2 + r * gh2);
    const float h2 = (1.f - z) * n + z * s_h[tid];
    g_hall[((size_t)t * B_ + b) * H_ + tid] = h2;
    if (t == T_ - 1) out[(size_t)B_ * T_ * V_ + b * H_ + tid] = h2;
    __syncthreads();
    s_h[tid] = h2;
    __syncthreads();
  }
}

// ---------------- one launch: logits for ALL (t,b) rows. grid (786, 25)
__global__ void k_logits(const float* __restrict__ out_b, float* __restrict__ out) {
  __shared__ float sh2[B_ * H_];
  const int tid = threadIdx.x, chunk = blockIdx.x, t = blockIdx.y;
  for (int i = tid; i < B_ * H_; i += 256) sh2[i] = g_hall[(size_t)t * B_ * H_ + i];
  __syncthreads();
  const int vl = tid & 63, wid = tid >> 6;
  const int v = chunk * 64 + vl;
  const bool valid = (v < V_);
  float acc[8];
  const float base = valid ? out_b[v] : 0.f;
#pragma unroll
  for (int bb = 0; bb < 8; ++bb) acc[bb] = valid ? base : -INFINITY;
  if (valid) {
    const ushort8* wrow = (const ushort8*)(g_wbf + (size_t)v * H_);
    const float4* sh4 = (const float4*)sh2;
    for (int k8 = 0; k8 < 32; ++k8) {
      const ushort8 w = wrow[k8];
      float wf[8];
#pragma unroll
      for (int j = 0; j < 8; ++j) wf[j] = bf2f(w[j]);
#pragma unroll
      for (int bb = 0; bb < 8; ++bb) {
        const int bidx = wid * 8 + bb;
        const float4 a = sh4[bidx * 64 + k8 * 2];
        const float4 c = sh4[bidx * 64 + k8 * 2 + 1];
        acc[bb] += wf[0] * a.x + wf[1] * a.y + wf[2] * a.z + wf[3] * a.w
                 + wf[4] * c.x + wf[5] * c.y + wf[6] * c.z + wf[7] * c.w;
      }
    }
#pragma unroll
    for (int bb = 0; bb < 8; ++bb) {
      const int r = (wid * 8 + bb) * T_ + t;
      out[(size_t)r * V_ + v] = acc[bb];
    }
  }
#pragma unroll
  for (int bb = 0; bb < 8; ++bb) {
    float m = acc[bb];
    for (int off = 32; off > 0; off >>= 1) m = fmaxf(m, __shfl_xor(m, off));
    const float e = valid ? expf(acc[bb] - m) : 0.f;
    float s = e;
    for (int off = 32; off > 0; off >>= 1) s += __shfl_xor(s, off);
    if (vl == 0) {
      const int r = (wid * 8 + bb) * T_ + t;
      g_pmax[(size_t)r * NCH + chunk] = m;
      g_psum[(size_t)r * NCH + chunk] = s;
    }
  }
}

// ---------------- one launch: lse + in-place log-softmax. grid (25, 800)
__global__ void k_write(float* __restrict__ out) {
  __shared__ float red[4];
  const int r = blockIdx.y;   // r = b*T + t
  const int tid = threadIdx.x;
  float m = -INFINITY;
  for (int i = tid; i < NCH; i += 256) m = fmaxf(m, g_pmax[(size_t)r * NCH + i]);
  for (int off = 32; off > 0; off >>= 1) m = fmaxf(m, __shfl_xor(m, off));
  if ((tid & 63) == 0) red[tid >> 6] = m;
  __syncthreads();
  m = fmaxf(fmaxf(red[0], red[1]), fmaxf(red[2], red[3]));
  __syncthreads();
  float s = 0.f;
  for (int i = tid; i < NCH; i += 256)
    s += g_psum[(size_t)r * NCH + i] * expf(g_pmax[(size_t)r * NCH + i] - m);
  for (int off = 32; off > 0; off >>= 1) s += __shfl_xor(s, off);
  if ((tid & 63) == 0) red[tid >> 6] = s;
  __syncthreads();
  s = red[0] + red[1] + red[2] + red[3];
  float lse = m + logf(s);
  if (!isfinite(lse)) lse = 0.f;
  const size_t obase = (size_t)r * V_;
  const int vbase = blockIdx.x * 2048;
#pragma unroll
  for (int j = 0; j < 8; ++j) {
    const int v = vbase + j * 256 + tid;
    if (v < V_) out[obase + v] = out[obase + v] - lse;
  }
}

extern "C" void kernel_launch(void* const* d_in, const int* in_sizes, int n_in,
                              void* d_out, int out_size, void* d_ws, size_t ws_size,
                              hipStream_t stream) {
  const float* enc_h  = (const float*)d_in[0];
  const float* keys   = (const float*)d_in[1];
  const int*   tgt    = (const int*)d_in[2];
  const float* emb    = (const float*)d_in[3];
  const float* Wa_w   = (const float*)d_in[4];
  const float* Wa_b   = (const float*)d_in[5];
  const float* Ua_w   = (const float*)d_in[6];
  const float* Ua_b   = (const float*)d_in[7];
  const float* Va_w   = (const float*)d_in[8];
  const float* Va_b   = (const float*)d_in[9];
  const float* W_ih   = (const float*)d_in[10];
  const float* b_ih   = (const float*)d_in[11];
  const float* W_hh   = (const float*)d_in[12];
  const float* b_hh   = (const float*)d_in[13];
  const float* out_w  = (const float*)d_in[14];
  const float* out_b  = (const float*)d_in[15];
  float* out = (float*)d_out;
  (void)d_ws; (void)ws_size;

  hipLaunchKernelGGL(k_setup, dim3(B_ * S_ + 2048), dim3(256), 0, stream,
                     keys, Ua_w, Ua_b, Wa_b, out_w, W_ih, W_hh, Wa_w);
  hipLaunchKernelGGL(k_gie, dim3(12, T_), dim3(256), 0, stream, tgt, emb, W_ih, b_ih);
  hipLaunchKernelGGL(k_recur, dim3(B_), dim3(256), 0, stream,
                     enc_h, Va_w, Va_b, keys, b_hh, out);
  hipLaunchKernelGGL(k_logits, dim3(NCH, T_), dim3(256), 0, stream, out_b, out);
  hipLaunchKernelGGL(k_write, dim3(25, NROW), dim3(256), 0, stream, out);
}

// Round 8
// 1052.464 us; speedup vs baseline: 5.4800x; 1.8004x over previous
//
#include <hip/hip_runtime.h>
#include <math.h>

#define B_ 32
#define S_ 50
#define H_ 256
#define T_ 25
#define V_ 50257
#define NCH 786   /* ceil(V/64) */
#define NROW (B_ * T_)
#define NWROW 1024  /* 256 Wa + 768 W_hh */
#define SOS 0

typedef unsigned short ushort_t;
typedef __attribute__((ext_vector_type(8))) unsigned short ushort8;

// ---- static device scratch (loader-allocated; fully rewritten each call)
__device__ ushort_t g_ua[B_ * S_ * H_];        // bf16 ua_keys + (Ua_b+Wa_b) folded
__device__ float    g_hall[T_ * B_ * H_];      // h2 for all steps, [t][b][g]
__device__ float    g_gie[T_ * B_ * 3 * H_];   // W_ih[:,:256].emb + b_ih
__device__ ushort_t g_wbf[(size_t)V_ * H_];    // out_w bf16
__device__ ushort_t g_wcat[NWROW * H_];        // packed bf16 [Wa; W_hh], K=256
__device__ ushort_t g_MT[B_ * S_ * 768];       // M^T[b][s][j] bf16, M = W_ihc.keys^T
__device__ float    g_pmax[NROW * NCH];
__device__ float    g_psum[NROW * NCH];

__device__ __forceinline__ float bf2f(ushort_t h) {
  union { unsigned int u; float f; } c; c.u = ((unsigned int)h) << 16; return c.f;
}
__device__ __forceinline__ ushort_t f2bf(float f) {
  union { float f; unsigned int u; } c; c.f = f;
  unsigned int u = c.u;
  return (ushort_t)((u + 0x7FFFu + ((u >> 16) & 1u)) >> 16);
}

// ---------------- one launch: ua GEMM (blocks 0..1599) + bf16 packs (blocks 1600..)
__global__ void k_setup(const float* __restrict__ keys, const float* __restrict__ Ua_w,
                        const float* __restrict__ Ua_b, const float* __restrict__ Wa_b,
                        const float* __restrict__ out_w, const float* __restrict__ W_hh,
                        const float* __restrict__ Wa_w) {
  const int bid = blockIdx.x, tid = threadIdx.x;
  if (bid < B_ * S_) {
    __shared__ float sk[H_];
    sk[tid] = keys[bid * H_ + tid];
    __syncthreads();
    float acc = Ua_b[tid] + Wa_b[tid];   // fold both biases into ua
    const float4* wrow = (const float4*)(Ua_w + (size_t)tid * H_);
    const float4* sk4 = (const float4*)sk;
    for (int k = 0; k < H_ / 4; ++k) {
      const float4 w = wrow[k], x = sk4[k];
      acc += w.x * x.x + w.y * x.y + w.z * x.z + w.w * x.w;
    }
    g_ua[(size_t)bid * H_ + tid] = f2bf(acc);
  } else {
    const int cb = bid - B_ * S_;
    const size_t i0 = (size_t)cb * 256 + tid;
    const size_t stride = 2048u * 256u;
    for (size_t i = i0; i < (size_t)V_ * H_; i += stride) g_wbf[i] = f2bf(out_w[i]);
    for (size_t i = i0; i < (size_t)NWROW * H_; i += stride) {
      const int r = (int)(i >> 8), k = (int)(i & 255);
      const float v = (r < 256) ? Wa_w[r * H_ + k] : W_hh[(r - 256) * H_ + k];
      g_wcat[i] = f2bf(v);
    }
  }
}

// ---------------- one launch: M^T[b][s][j] = W_ih[j,256:] . keys[b,s,:]
// grid (12, 32); block: 16 groups x 16 lanes; strided-k mapping (conflict-free LDS)
__global__ void k_m(const float* __restrict__ keys, const float* __restrict__ W_ih) {
  __shared__ float sk[S_ * H_];   // 50 KB
  const int c = blockIdx.x, b = blockIdx.y, tid = threadIdx.x;
  {
    const float4* src = (const float4*)(keys + (size_t)b * S_ * H_);
    float4* dst = (float4*)sk;
    for (int i = tid; i < S_ * H_ / 4; i += 256) dst[i] = src[i];
  }
  __syncthreads();
  const int sub = tid & 15, grp = tid >> 4;
#pragma unroll 1
  for (int it = 0; it < 4; ++it) {
    const int j = c * 64 + it * 16 + grp;
    float w16[16];
#pragma unroll
    for (int kp = 0; kp < 16; ++kp)
      w16[kp] = W_ih[(size_t)j * (2 * H_) + H_ + sub + 16 * kp];
#pragma unroll 1
    for (int s = 0; s < S_; ++s) {
      float a = 0.f;
#pragma unroll
      for (int kp = 0; kp < 16; ++kp) a += w16[kp] * sk[s * H_ + sub + 16 * kp];
      a += __shfl_xor(a, 8); a += __shfl_xor(a, 4);
      a += __shfl_xor(a, 2); a += __shfl_xor(a, 1);
      if (sub == 0) g_MT[((size_t)b * S_ + s) * 768 + j] = f2bf(a);
    }
  }
}

// ---------------- one launch: gie[t][b][j] = emb(tok[t,b]) . W_ih[j,:256] + b_ih[j]
__global__ void k_gie(const int* __restrict__ tgt, const float* __restrict__ emb_tab,
                      const float* __restrict__ W_ih, const float* __restrict__ b_ih) {
  __shared__ float semb[B_ * H_];
  const int tid = threadIdx.x, chunk = blockIdx.x, t = blockIdx.y;
  for (int i = tid; i < B_ * H_; i += 256) {
    const int b = i >> 8, g = i & 255;
    const int tok = (t == 0) ? SOS : tgt[b * T_ + (t - 1)];
    semb[i] = emb_tab[(size_t)tok * H_ + g];
  }
  __syncthreads();
  const int vl = tid & 63, wd = tid >> 6;
  const int j = chunk * 64 + vl;
  const float4* wrow = (const float4*)(W_ih + (size_t)j * (2 * H_));
  const float4* se4 = (const float4*)semb;
  float acc[8];
  const float base = b_ih[j];
#pragma unroll
  for (int bb = 0; bb < 8; ++bb) acc[bb] = base;
  for (int k4 = 0; k4 < 64; ++k4) {
    const float4 w = wrow[k4];
#pragma unroll
    for (int bb = 0; bb < 8; ++bb) {
      const float4 x = se4[(wd * 8 + bb) * 64 + k4];
      acc[bb] += w.x * x.x + w.y * x.y + w.z * x.z + w.w * x.w;
    }
  }
#pragma unroll
  for (int bb = 0; bb < 8; ++bb)
    g_gie[((size_t)t * B_ + (wd * 8 + bb)) * (3 * H_) + j] = acc[bb];
}

// ---------------- ONE launch, whole recurrence. 32 blocks x 1024 threads (16 waves).
__global__ void __launch_bounds__(1024, 1)
k_recur(const float* __restrict__ enc_h, const float* __restrict__ Va_w,
        const float* __restrict__ Va_b, const float* __restrict__ b_hh,
        float* __restrict__ out) {
  __shared__ ushort_t s_ua[S_ * H_];   // 25.6 KB bf16
  __shared__ ushort_t s_M[S_ * 768];   // 76.8 KB bf16  [s][j]
  __shared__ float s_res[NWROW];       // 4 KB: [0,256)=Wa.h, [256,1024)=W_hh.h
  __shared__ float s_mw[768];          // 3 KB: M.w
  __shared__ float s_h[H_];
  __shared__ float s_va[H_];
  __shared__ float s_score[64], s_w[64];
  const int b = blockIdx.x, tid = threadIdx.x;
  const int lane = tid & 63, wid = tid >> 6;
  const int sub = lane & 15;
  const int grp = tid >> 4;            // 0..63 row-slot (within-wave groups of 16)

  {
    const uint4* src = (const uint4*)(g_ua + (size_t)b * S_ * H_);
    uint4* dst = (uint4*)s_ua;
    for (int i = tid; i < S_ * H_ / 8; i += 1024) dst[i] = src[i];
    const uint4* src2 = (const uint4*)(g_MT + (size_t)b * S_ * 768);
    uint4* dst2 = (uint4*)s_M;
    for (int i = tid; i < S_ * 768 / 8; i += 1024) dst2[i] = src2[i];
  }
  if (tid < H_) {
    s_h[tid] = enc_h[b * H_ + tid];
    s_va[tid] = Va_w[tid];
  }
  const float vab = Va_b[0];
  float bhh0 = 0.f, bhh1 = 0.f, bhh2 = 0.f;
  if (tid < H_) {
    bhh0 = b_hh[tid]; bhh1 = b_hh[H_ + tid]; bhh2 = b_hh[2 * H_ + tid];
  }
  __syncthreads();

  for (int t = 0; t < T_; ++t) {
    // ---- sweep rows [0,1024): vec = h. 64 rows/iter (16 waves x 4), 16 iters.
#pragma unroll 2
    for (int it = 0; it < 16; ++it) {
      const int row = it * 64 + grp;
      const ushort8* wr = (const ushort8*)(g_wcat + (size_t)row * H_);
      const ushort8 w0 = wr[sub], w1 = wr[16 + sub];
      const float* v0 = s_h + sub * 8;
      const float* v1 = s_h + 128 + sub * 8;
      float a0 = 0.f, a1 = 0.f;
#pragma unroll
      for (int j = 0; j < 8; ++j) { a0 += bf2f(w0[j]) * v0[j]; a1 += bf2f(w1[j]) * v1[j]; }
      float a = a0 + a1;
      a += __shfl_xor(a, 8); a += __shfl_xor(a, 4);
      a += __shfl_xor(a, 2); a += __shfl_xor(a, 1);
      if (sub == 0) s_res[row] = a;
    }
    __syncthreads();

    // ---- attention scores: sum_g tanh(wq[g]+ua[s,g])*va[g] ; 16 waves split s
    for (int s = wid; s < S_; s += 16) {
      const ushort_t* uarow = s_ua + s * H_;
      float acc = 0.f;
#pragma unroll
      for (int i = 0; i < 4; ++i) {
        const int gg = lane + i * 64;
        acc += tanhf(s_res[gg] + bf2f(uarow[gg])) * s_va[gg];
      }
      for (int off = 32; off > 0; off >>= 1) acc += __shfl_xor(acc, off);
      if (lane == 0) s_score[s] = acc + vab;
    }
    __syncthreads();

    // ---- softmax over S on wave 0; write attention output
    if (tid < 64) {
      const float v = (tid < S_) ? s_score[tid] : -INFINITY;
      float m = v;
      for (int off = 32; off > 0; off >>= 1) m = fmaxf(m, __shfl_xor(m, off));
      const float e = (tid < S_) ? expf(v - m) : 0.f;
      float ssum = e;
      for (int off = 32; off > 0; off >>= 1) ssum += __shfl_xor(ssum, off);
      const float w = e / ssum;
      if (tid < S_) {
        s_w[tid] = w;
        out[(size_t)B_ * T_ * V_ + (size_t)B_ * H_ + (size_t)(b * T_ + t) * S_ + tid] = w;
      }
    }
    __syncthreads();

    // ---- gi_ctx = M . w  (768 threads, 50-term LDS matvec)
    if (tid < 768) {
      float acc = 0.f;
#pragma unroll 1
      for (int s = 0; s < S_; ++s) acc += bf2f(s_M[s * 768 + tid]) * s_w[s];
      s_mw[tid] = acc;
    }
    __syncthreads();

    // ---- GRU finish: threads 0..255 own unit g=tid
    if (tid < H_) {
      const float* gie = g_gie + ((size_t)t * B_ + b) * (3 * H_);
      const float gi0 = gie[tid] + s_mw[tid];
      const float gi1 = gie[H_ + tid] + s_mw[H_ + tid];
      const float gi2 = gie[2 * H_ + tid] + s_mw[2 * H_ + tid];
      const float gh0 = s_res[256 + tid] + bhh0;
      const float gh1 = s_res[512 + tid] + bhh1;
      const float gh2 = s_res[768 + tid] + bhh2;
      const float r = 1.f / (1.f + expf(-(gi0 + gh0)));
      const float z = 1.f / (1.f + expf(-(gi1 + gh1)));
      const float n = tanhf(gi2 + r * gh2);
      const float h2 = (1.f - z) * n + z * s_h[tid];
      g_hall[((size_t)t * B_ + b) * H_ + tid] = h2;
      if (t == T_ - 1) out[(size_t)B_ * T_ * V_ + b * H_ + tid] = h2;
    }
    __syncthreads();
    if (tid < H_) {
      const float h2 = g_hall[((size_t)t * B_ + b) * H_ + tid];
      s_h[tid] = h2;
    }
    __syncthreads();
  }
}

// ---------------- one launch: logits for ALL (t,b) rows. grid (786, 25)
__global__ void k_logits(const float* __restrict__ out_b, float* __restrict__ out) {
  __shared__ float sh2[B_ * H_];
  const int tid = threadIdx.x, chunk = blockIdx.x, t = blockIdx.y;
  for (int i = tid; i < B_ * H_; i += 256) sh2[i] = g_hall[(size_t)t * B_ * H_ + i];
  __syncthreads();
  const int vl = tid & 63, wid = tid >> 6;
  const int v = chunk * 64 + vl;
  const bool valid = (v < V_);
  float acc[8];
  const float base = valid ? out_b[v] : 0.f;
#pragma unroll
  for (int bb = 0; bb < 8; ++bb) acc[bb] = valid ? base : -INFINITY;
  if (valid) {
    const ushort8* wrow = (const ushort8*)(g_wbf + (size_t)v * H_);
    const float4* sh4 = (const float4*)sh2;
    for (int k8 = 0; k8 < 32; ++k8) {
      const ushort8 w = wrow[k8];
      float wf[8];
#pragma unroll
      for (int j = 0; j < 8; ++j) wf[j] = bf2f(w[j]);
#pragma unroll
      for (int bb = 0; bb < 8; ++bb) {
        const int bidx = wid * 8 + bb;
        const float4 a = sh4[bidx * 64 + k8 * 2];
        const float4 c = sh4[bidx * 64 + k8 * 2 + 1];
        acc[bb] += wf[0] * a.x + wf[1] * a.y + wf[2] * a.z + wf[3] * a.w
                 + wf[4] * c.x + wf[5] * c.y + wf[6] * c.z + wf[7] * c.w;
      }
    }
#pragma unroll
    for (int bb = 0; bb < 8; ++bb) {
      const int r = (wid * 8 + bb) * T_ + t;
      out[(size_t)r * V_ + v] = acc[bb];
    }
  }
#pragma unroll
  for (int bb = 0; bb < 8; ++bb) {
    float m = acc[bb];
    for (int off = 32; off > 0; off >>= 1) m = fmaxf(m, __shfl_xor(m, off));
    const float e = valid ? expf(acc[bb] - m) : 0.f;
    float s = e;
    for (int off = 32; off > 0; off >>= 1) s += __shfl_xor(s, off);
    if (vl == 0) {
      const int r = (wid * 8 + bb) * T_ + t;
      g_pmax[(size_t)r * NCH + chunk] = m;
      g_psum[(size_t)r * NCH + chunk] = s;
    }
  }
}

// ---------------- one launch: lse + in-place log-softmax. grid (25, 800)
__global__ void k_write(float* __restrict__ out) {
  __shared__ float red[4];
  const int r = blockIdx.y;   // r = b*T + t
  const int tid = threadIdx.x;
  float m = -INFINITY;
  for (int i = tid; i < NCH; i += 256) m = fmaxf(m, g_pmax[(size_t)r * NCH + i]);
  for (int off = 32; off > 0; off >>= 1) m = fmaxf(m, __shfl_xor(m, off));
  if ((tid & 63) == 0) red[tid >> 6] = m;
  __syncthreads();
  m = fmaxf(fmaxf(red[0], red[1]), fmaxf(red[2], red[3]));
  __syncthreads();
  float s = 0.f;
  for (int i = tid; i < NCH; i += 256)
    s += g_psum[(size_t)r * NCH + i] * expf(g_pmax[(size_t)r * NCH + i] - m);
  for (int off = 32; off > 0; off >>= 1) s += __shfl_xor(s, off);
  if ((tid & 63) == 0) red[tid >> 6] = s;
  __syncthreads();
  s = red[0] + red[1] + red[2] + red[3];
  float lse = m + logf(s);
  if (!isfinite(lse)) lse = 0.f;
  const size_t obase = (size_t)r * V_;
  const int vbase = blockIdx.x * 2048;
#pragma unroll
  for (int j = 0; j < 8; ++j) {
    const int v = vbase + j * 256 + tid;
    if (v < V_) out[obase + v] = out[obase + v] - lse;
  }
}

extern "C" void kernel_launch(void* const* d_in, const int* in_sizes, int n_in,
                              void* d_out, int out_size, void* d_ws, size_t ws_size,
                              hipStream_t stream) {
  const float* enc_h  = (const float*)d_in[0];
  const float* keys   = (const float*)d_in[1];
  const int*   tgt    = (const int*)d_in[2];
  const float* emb    = (const float*)d_in[3];
  const float* Wa_w   = (const float*)d_in[4];
  const float* Wa_b   = (const float*)d_in[5];
  const float* Ua_w   = (const float*)d_in[6];
  const float* Ua_b   = (const float*)d_in[7];
  const float* Va_w   = (const float*)d_in[8];
  const float* Va_b   = (const float*)d_in[9];
  const float* W_ih   = (const float*)d_in[10];
  const float* b_ih   = (const float*)d_in[11];
  const float* W_hh   = (const float*)d_in[12];
  const float* b_hh   = (const float*)d_in[13];
  const float* out_w  = (const float*)d_in[14];
  const float* out_b  = (const float*)d_in[15];
  float* out = (float*)d_out;
  (void)d_ws; (void)ws_size;

  hipLaunchKernelGGL(k_setup, dim3(B_ * S_ + 2048), dim3(256), 0, stream,
                     keys, Ua_w, Ua_b, Wa_b, out_w, W_hh, Wa_w);
  hipLaunchKernelGGL(k_m, dim3(12, B_), dim3(256), 0, stream, keys, W_ih);
  hipLaunchKernelGGL(k_gie, dim3(12, T_), dim3(256), 0, stream, tgt, emb, W_ih, b_ih);
  hipLaunchKernelGGL(k_recur, dim3(B_), dim3(1024), 0, stream,
                     enc_h, Va_w, Va_b, b_hh, out);
  hipLaunchKernelGGL(k_logits, dim3(NCH, T_), dim3(256), 0, stream, out_b, out);
  hipLaunchKernelGGL(k_write, dim3(25, NROW), dim3(256), 0, stream, out);
}

// Round 9
// 660.947 us; speedup vs baseline: 8.7261x; 1.5924x over previous
//
#include <hip/hip_runtime.h>
#include <math.h>

#define B_ 32
#define S_ 50
#define H_ 256
#define T_ 25
#define V_ 50257
#define NCH 786   /* 393 n-blocks x 2 wave-cols */
#define NROW (B_ * T_)
#define NWROW 1024  /* 256 Wa + 768 W_hh */
#define SOS 0

typedef unsigned short ushort_t;
typedef __attribute__((ext_vector_type(8))) unsigned short ushort8;
typedef __attribute__((ext_vector_type(8))) short short8v;
typedef __attribute__((ext_vector_type(4))) float f32x4;

// ---- static device scratch (loader-allocated; fully rewritten each call)
__device__ ushort_t g_ua[B_ * S_ * H_];        // bf16 ua_keys + (Ua_b+Wa_b) folded
__device__ ushort_t g_hbf[NROW * H_];          // bf16 h2, row m = b*T+t
__device__ float    g_gie[T_ * B_ * 3 * H_];   // W_ih[:,:256].emb + b_ih
__device__ ushort_t g_wbf[(size_t)V_ * H_];    // out_w bf16
__device__ ushort_t g_wcat[NWROW * H_];        // packed bf16 [Wa; W_hh], K=256
__device__ ushort_t g_MT[B_ * S_ * 768];       // M^T[b][s][j] bf16, M = W_ihc.keys^T
__device__ float    g_pmax[NROW * NCH];
__device__ float    g_psum[NROW * NCH];

__device__ __forceinline__ float bf2f(ushort_t h) {
  union { unsigned int u; float f; } c; c.u = ((unsigned int)h) << 16; return c.f;
}
__device__ __forceinline__ ushort_t f2bf(float f) {
  union { float f; unsigned int u; } c; c.f = f;
  unsigned int u = c.u;
  return (ushort_t)((u + 0x7FFFu + ((u >> 16) & 1u)) >> 16);
}

// ---------------- one launch: ua GEMM (blocks 0..1599) + bf16 packs (blocks 1600..)
__global__ void k_setup(const float* __restrict__ keys, const float* __restrict__ Ua_w,
                        const float* __restrict__ Ua_b, const float* __restrict__ Wa_b,
                        const float* __restrict__ out_w, const float* __restrict__ W_hh,
                        const float* __restrict__ Wa_w) {
  const int bid = blockIdx.x, tid = threadIdx.x;
  if (bid < B_ * S_) {
    __shared__ float sk[H_];
    sk[tid] = keys[bid * H_ + tid];
    __syncthreads();
    float acc = Ua_b[tid] + Wa_b[tid];
    const float4* wrow = (const float4*)(Ua_w + (size_t)tid * H_);
    const float4* sk4 = (const float4*)sk;
    for (int k = 0; k < H_ / 4; ++k) {
      const float4 w = wrow[k], x = sk4[k];
      acc += w.x * x.x + w.y * x.y + w.z * x.z + w.w * x.w;
    }
    g_ua[(size_t)bid * H_ + tid] = f2bf(acc);
  } else {
    const int cb = bid - B_ * S_;
    const size_t i0 = (size_t)cb * 256 + tid;
    const size_t stride = 2048u * 256u;
    for (size_t i = i0; i < (size_t)V_ * H_; i += stride) g_wbf[i] = f2bf(out_w[i]);
    for (size_t i = i0; i < (size_t)NWROW * H_; i += stride) {
      const int r = (int)(i >> 8), k = (int)(i & 255);
      const float v = (r < 256) ? Wa_w[r * H_ + k] : W_hh[(r - 256) * H_ + k];
      g_wcat[i] = f2bf(v);
    }
  }
}

// ---------------- one launch: M^T[b][s][j] = W_ih[j,256:] . keys[b,s,:]
__global__ void k_m(const float* __restrict__ keys, const float* __restrict__ W_ih) {
  __shared__ float sk[S_ * H_];
  const int c = blockIdx.x, b = blockIdx.y, tid = threadIdx.x;
  {
    const float4* src = (const float4*)(keys + (size_t)b * S_ * H_);
    float4* dst = (float4*)sk;
    for (int i = tid; i < S_ * H_ / 4; i += 256) dst[i] = src[i];
  }
  __syncthreads();
  const int sub = tid & 15, grp = tid >> 4;
#pragma unroll 1
  for (int it = 0; it < 4; ++it) {
    const int j = c * 64 + it * 16 + grp;
    float w16[16];
#pragma unroll
    for (int kp = 0; kp < 16; ++kp)
      w16[kp] = W_ih[(size_t)j * (2 * H_) + H_ + sub + 16 * kp];
#pragma unroll 1
    for (int s = 0; s < S_; ++s) {
      float a = 0.f;
#pragma unroll
      for (int kp = 0; kp < 16; ++kp) a += w16[kp] * sk[s * H_ + sub + 16 * kp];
      a += __shfl_xor(a, 8); a += __shfl_xor(a, 4);
      a += __shfl_xor(a, 2); a += __shfl_xor(a, 1);
      if (sub == 0) g_MT[((size_t)b * S_ + s) * 768 + j] = f2bf(a);
    }
  }
}

// ---------------- one launch: gie[t][b][j] = emb(tok[t,b]) . W_ih[j,:256] + b_ih[j]
__global__ void k_gie(const int* __restrict__ tgt, const float* __restrict__ emb_tab,
                      const float* __restrict__ W_ih, const float* __restrict__ b_ih) {
  __shared__ float semb[B_ * H_];
  const int tid = threadIdx.x, chunk = blockIdx.x, t = blockIdx.y;
  for (int i = tid; i < B_ * H_; i += 256) {
    const int b = i >> 8, g = i & 255;
    const int tok = (t == 0) ? SOS : tgt[b * T_ + (t - 1)];
    semb[i] = emb_tab[(size_t)tok * H_ + g];
  }
  __syncthreads();
  const int vl = tid & 63, wd = tid >> 6;
  const int j = chunk * 64 + vl;
  const float4* wrow = (const float4*)(W_ih + (size_t)j * (2 * H_));
  const float4* se4 = (const float4*)semb;
  float acc[8];
  const float base = b_ih[j];
#pragma unroll
  for (int bb = 0; bb < 8; ++bb) acc[bb] = base;
  for (int k4 = 0; k4 < 64; ++k4) {
    const float4 w = wrow[k4];
#pragma unroll
    for (int bb = 0; bb < 8; ++bb) {
      const float4 x = se4[(wd * 8 + bb) * 64 + k4];
      acc[bb] += w.x * x.x + w.y * x.y + w.z * x.z + w.w * x.w;
    }
  }
#pragma unroll
  for (int bb = 0; bb < 8; ++bb)
    g_gie[((size_t)t * B_ + (wd * 8 + bb)) * (3 * H_) + j] = acc[bb];
}

// ---------------- ONE launch, whole recurrence. 32 blocks x 1024 threads.
__global__ void __launch_bounds__(1024, 1)
k_recur(const float* __restrict__ enc_h, const float* __restrict__ Va_w,
        const float* __restrict__ Va_b, const float* __restrict__ b_hh,
        float* __restrict__ out) {
  __shared__ ushort_t s_ua[S_ * H_];
  __shared__ ushort_t s_M[S_ * 768];
  __shared__ float s_res[NWROW];
  __shared__ float s_mw[768];
  __shared__ float s_h[H_];
  __shared__ float s_va[H_];
  __shared__ float s_score[64], s_w[64];
  const int b = blockIdx.x, tid = threadIdx.x;
  const int lane = tid & 63, wid = tid >> 6;
  const int sub = lane & 15;
  const int grp = tid >> 4;

  {
    const uint4* src = (const uint4*)(g_ua + (size_t)b * S_ * H_);
    uint4* dst = (uint4*)s_ua;
    for (int i = tid; i < S_ * H_ / 8; i += 1024) dst[i] = src[i];
    const uint4* src2 = (const uint4*)(g_MT + (size_t)b * S_ * 768);
    uint4* dst2 = (uint4*)s_M;
    for (int i = tid; i < S_ * 768 / 8; i += 1024) dst2[i] = src2[i];
  }
  if (tid < H_) {
    s_h[tid] = enc_h[b * H_ + tid];
    s_va[tid] = Va_w[tid];
  }
  const float vab = Va_b[0];
  float bhh0 = 0.f, bhh1 = 0.f, bhh2 = 0.f;
  if (tid < H_) {
    bhh0 = b_hh[tid]; bhh1 = b_hh[H_ + tid]; bhh2 = b_hh[2 * H_ + tid];
  }
  __syncthreads();

  for (int t = 0; t < T_; ++t) {
#pragma unroll 2
    for (int it = 0; it < 16; ++it) {
      const int row = it * 64 + grp;
      const ushort8* wr = (const ushort8*)(g_wcat + (size_t)row * H_);
      const ushort8 w0 = wr[sub], w1 = wr[16 + sub];
      const float* v0 = s_h + sub * 8;
      const float* v1 = s_h + 128 + sub * 8;
      float a0 = 0.f, a1 = 0.f;
#pragma unroll
      for (int j = 0; j < 8; ++j) { a0 += bf2f(w0[j]) * v0[j]; a1 += bf2f(w1[j]) * v1[j]; }
      float a = a0 + a1;
      a += __shfl_xor(a, 8); a += __shfl_xor(a, 4);
      a += __shfl_xor(a, 2); a += __shfl_xor(a, 1);
      if (sub == 0) s_res[row] = a;
    }
    __syncthreads();

    for (int s = wid; s < S_; s += 16) {
      const ushort_t* uarow = s_ua + s * H_;
      float acc = 0.f;
#pragma unroll
      for (int i = 0; i < 4; ++i) {
        const int gg = lane + i * 64;
        acc += tanhf(s_res[gg] + bf2f(uarow[gg])) * s_va[gg];
      }
      for (int off = 32; off > 0; off >>= 1) acc += __shfl_xor(acc, off);
      if (lane == 0) s_score[s] = acc + vab;
    }
    __syncthreads();

    if (tid < 64) {
      const float v = (tid < S_) ? s_score[tid] : -INFINITY;
      float m = v;
      for (int off = 32; off > 0; off >>= 1) m = fmaxf(m, __shfl_xor(m, off));
      const float e = (tid < S_) ? expf(v - m) : 0.f;
      float ssum = e;
      for (int off = 32; off > 0; off >>= 1) ssum += __shfl_xor(ssum, off);
      const float w = e / ssum;
      if (tid < S_) {
        s_w[tid] = w;
        out[(size_t)B_ * T_ * V_ + (size_t)B_ * H_ + (size_t)(b * T_ + t) * S_ + tid] = w;
      }
    }
    __syncthreads();

    if (tid < 768) {
      float acc = 0.f;
#pragma unroll 1
      for (int s = 0; s < S_; ++s) acc += bf2f(s_M[s * 768 + tid]) * s_w[s];
      s_mw[tid] = acc;
    }
    __syncthreads();

    float h2 = 0.f;
    if (tid < H_) {
      const float* gie = g_gie + ((size_t)t * B_ + b) * (3 * H_);
      const float gi0 = gie[tid] + s_mw[tid];
      const float gi1 = gie[H_ + tid] + s_mw[H_ + tid];
      const float gi2 = gie[2 * H_ + tid] + s_mw[2 * H_ + tid];
      const float gh0 = s_res[256 + tid] + bhh0;
      const float gh1 = s_res[512 + tid] + bhh1;
      const float gh2 = s_res[768 + tid] + bhh2;
      const float r = 1.f / (1.f + expf(-(gi0 + gh0)));
      const float z = 1.f / (1.f + expf(-(gi1 + gh1)));
      const float n = tanhf(gi2 + r * gh2);
      h2 = (1.f - z) * n + z * s_h[tid];
      g_hbf[((size_t)b * T_ + t) * H_ + tid] = f2bf(h2);
      if (t == T_ - 1) out[(size_t)B_ * T_ * V_ + b * H_ + tid] = h2;
    }
    __syncthreads();
    if (tid < H_) s_h[tid] = h2;
    __syncthreads();
  }
}

// ---------------- MFMA logits GEMM: C[800,50257] = h_bf16 . out_w^T (+bias) + partials
// grid (393, 7), block 256 (4 waves, 2x2 of 64x64). K=256 in 8 steps of 32.
__global__ void __launch_bounds__(256, 2)
k_logits(const float* __restrict__ out_b, float* __restrict__ out) {
  __shared__ ushort_t sA[128 * 256];   // 64 KB bf16, XOR-swizzled rows
  const int tid = threadIdx.x;
  const int n0 = blockIdx.x * 128, m0 = blockIdx.y * 128;
  const int lane = tid & 63, wv = tid >> 6;
  const int wm = wv >> 1, wn = wv & 1;
  const int l16 = lane & 15, l4 = lane >> 4;

  // stage A-tile (128 rows x 256 k), zero-pad rows >= 800
  for (int i = tid; i < 128 * 32; i += 256) {
    const int row = i >> 5, ks = i & 31;
    const int m = m0 + row;
    ushort8 val;
    if (m < NROW) val = ((const ushort8*)(g_hbf + (size_t)m * H_))[ks];
    else { ushort8 z = {0,0,0,0,0,0,0,0}; val = z; }
    *(ushort8*)((char*)sA + row * 512 + ((ks ^ (row & 7)) << 4)) = val;
  }
  __syncthreads();

  f32x4 acc[4][4];
#pragma unroll
  for (int mi = 0; mi < 4; ++mi)
#pragma unroll
    for (int ni = 0; ni < 4; ++ni) acc[mi][ni] = (f32x4){0.f, 0.f, 0.f, 0.f};

#pragma unroll 1
  for (int kk = 0; kk < 8; ++kk) {
    short8v a[4], bfr[4];
#pragma unroll
    for (int mi = 0; mi < 4; ++mi) {
      const int row = wm * 64 + mi * 16 + l16;
      const int ks = kk * 4 + l4;
      a[mi] = *(const short8v*)((const char*)sA + row * 512 + ((ks ^ (row & 7)) << 4));
    }
#pragma unroll
    for (int ni = 0; ni < 4; ++ni) {
      const int v = n0 + wn * 64 + ni * 16 + l16;
      const int vc = (v < V_) ? v : 0;
      bfr[ni] = ((const short8v*)(g_wbf + (size_t)vc * H_))[kk * 4 + l4];
    }
#pragma unroll
    for (int mi = 0; mi < 4; ++mi)
#pragma unroll
      for (int ni = 0; ni < 4; ++ni)
        acc[mi][ni] = __builtin_amdgcn_mfma_f32_16x16x32_bf16(a[mi], bfr[ni], acc[mi][ni], 0, 0, 0);
  }

  // epilogue: bias, row-max/sum-exp partials via 16-lane xor reduce, stores
  int vcol[4]; float bias[4]; bool valid[4];
#pragma unroll
  for (int ni = 0; ni < 4; ++ni) {
    vcol[ni] = n0 + wn * 64 + ni * 16 + l16;
    valid[ni] = (vcol[ni] < V_);
    bias[ni] = valid[ni] ? out_b[vcol[ni]] : 0.f;
  }
  const int chunk = blockIdx.x * 2 + wn;
#pragma unroll
  for (int mi = 0; mi < 4; ++mi) {
#pragma unroll
    for (int j = 0; j < 4; ++j) {
      const int m = m0 + wm * 64 + mi * 16 + l4 * 4 + j;
      float vv[4];
      float mx = -INFINITY;
#pragma unroll
      for (int ni = 0; ni < 4; ++ni) {
        vv[ni] = acc[mi][ni][j] + bias[ni];
        if (valid[ni]) mx = fmaxf(mx, vv[ni]);
      }
      mx = fmaxf(mx, __shfl_xor(mx, 1)); mx = fmaxf(mx, __shfl_xor(mx, 2));
      mx = fmaxf(mx, __shfl_xor(mx, 4)); mx = fmaxf(mx, __shfl_xor(mx, 8));
      float es = 0.f;
#pragma unroll
      for (int ni = 0; ni < 4; ++ni) if (valid[ni]) es += expf(vv[ni] - mx);
      es += __shfl_xor(es, 1); es += __shfl_xor(es, 2);
      es += __shfl_xor(es, 4); es += __shfl_xor(es, 8);
      if (m < NROW) {
#pragma unroll
        for (int ni = 0; ni < 4; ++ni)
          if (valid[ni]) out[(size_t)m * V_ + vcol[ni]] = vv[ni];
        if (l16 == 0) {
          g_pmax[(size_t)m * NCH + chunk] = mx;
          g_psum[(size_t)m * NCH + chunk] = es;
        }
      }
    }
  }
}

// ---------------- one launch: lse + in-place log-softmax. grid (25, 800)
__global__ void k_write(float* __restrict__ out) {
  __shared__ float red[4];
  const int r = blockIdx.y;
  const int tid = threadIdx.x;
  float m = -INFINITY;
  for (int i = tid; i < NCH; i += 256) m = fmaxf(m, g_pmax[(size_t)r * NCH + i]);
  for (int off = 32; off > 0; off >>= 1) m = fmaxf(m, __shfl_xor(m, off));
  if ((tid & 63) == 0) red[tid >> 6] = m;
  __syncthreads();
  m = fmaxf(fmaxf(red[0], red[1]), fmaxf(red[2], red[3]));
  __syncthreads();
  float s = 0.f;
  for (int i = tid; i < NCH; i += 256)
    s += g_psum[(size_t)r * NCH + i] * expf(g_pmax[(size_t)r * NCH + i] - m);
  for (int off = 32; off > 0; off >>= 1) s += __shfl_xor(s, off);
  if ((tid & 63) == 0) red[tid >> 6] = s;
  __syncthreads();
  s = red[0] + red[1] + red[2] + red[3];
  float lse = m + logf(s);
  if (!isfinite(lse)) lse = 0.f;
  const size_t obase = (size_t)r * V_;
  const int vbase = blockIdx.x * 2048;
#pragma unroll
  for (int j = 0; j < 8; ++j) {
    const int v = vbase + j * 256 + tid;
    if (v < V_) out[obase + v] = out[obase + v] - lse;
  }
}

extern "C" void kernel_launch(void* const* d_in, const int* in_sizes, int n_in,
                              void* d_out, int out_size, void* d_ws, size_t ws_size,
                              hipStream_t stream) {
  const float* enc_h  = (const float*)d_in[0];
  const float* keys   = (const float*)d_in[1];
  const int*   tgt    = (const int*)d_in[2];
  const float* emb    = (const float*)d_in[3];
  const float* Wa_w   = (const float*)d_in[4];
  const float* Wa_b   = (const float*)d_in[5];
  const float* Ua_w   = (const float*)d_in[6];
  const float* Ua_b   = (const float*)d_in[7];
  const float* Va_w   = (const float*)d_in[8];
  const float* Va_b   = (const float*)d_in[9];
  const float* W_ih   = (const float*)d_in[10];
  const float* b_ih   = (const float*)d_in[11];
  const float* W_hh   = (const float*)d_in[12];
  const float* b_hh   = (const float*)d_in[13];
  const float* out_w  = (const float*)d_in[14];
  const float* out_b  = (const float*)d_in[15];
  float* out = (float*)d_out;
  (void)d_ws; (void)ws_size;

  hipLaunchKernelGGL(k_setup, dim3(B_ * S_ + 2048), dim3(256), 0, stream,
                     keys, Ua_w, Ua_b, Wa_b, out_w, W_hh, Wa_w);
  hipLaunchKernelGGL(k_m, dim3(12, B_), dim3(256), 0, stream, keys, W_ih);
  hipLaunchKernelGGL(k_gie, dim3(12, T_), dim3(256), 0, stream, tgt, emb, W_ih, b_ih);
  hipLaunchKernelGGL(k_recur, dim3(B_), dim3(1024), 0, stream,
                     enc_h, Va_w, Va_b, b_hh, out);
  hipLaunchKernelGGL(k_logits, dim3(393, 7), dim3(256), 0, stream, out_b, out);
  hipLaunchKernelGGL(k_write, dim3(25, NROW), dim3(256), 0, stream, out);
}